// Round 11
// baseline (589.646 us; speedup 1.0000x reference)
//
#include <hip/hip_runtime.h>

// out = relu(concat(nf, prompt[bidx]) @ W1 + b1) @ W2 + b2
//   P2  = gp @ W1[512:] + b1               (tiny)
//   h   = relu(nf @ W1[:512] + P2[bidx])   (g1)
//   out = h @ W2 + b2                      (g2)
// Round 11: T14 all-reg-staged single-buffer GEMMs. Per step: issue loads(t+1)
// BEFORE compute(t); ds_write(t+1) AFTER; 2 raw barriers; no vmcnt drain exists.
// 2 m-tiles per block (16 continuous K-steps) amortize pipeline fill.

#define N_NODES 100000
#define NWG 1564   // 391 groups x 4 nt; groups of 2 m-tiles (782 mt total)

typedef __bf16 bf16x8 __attribute__((ext_vector_type(8)));
typedef float  f32x4  __attribute__((ext_vector_type(4)));
typedef unsigned short ushort_t;

__device__ __forceinline__ ushort_t f2bf(float f) {
  __bf16 b = (__bf16)f;
  return __builtin_bit_cast(unsigned short, b);
}

__device__ __forceinline__ bf16x8 cvt8(const float* p) {
  float4 x = *(const float4*)p;
  float4 y = *(const float4*)(p + 4);
  bf16x8 v;
  v[0] = (__bf16)x.x; v[1] = (__bf16)x.y; v[2] = (__bf16)x.z; v[3] = (__bf16)x.w;
  v[4] = (__bf16)y.x; v[5] = (__bf16)y.y; v[6] = (__bf16)y.z; v[7] = (__bf16)y.w;
  return v;
}

__device__ __forceinline__ bf16x8 cvt8v(float4 x, float4 y) {
  bf16x8 v;
  v[0] = (__bf16)x.x; v[1] = (__bf16)x.y; v[2] = (__bf16)x.z; v[3] = (__bf16)x.w;
  v[4] = (__bf16)y.x; v[5] = (__bf16)y.y; v[6] = (__bf16)y.z; v[7] = (__bf16)y.w;
  return v;
}

__device__ __forceinline__ void block_sync() {
  __builtin_amdgcn_sched_barrier(0);
  __builtin_amdgcn_s_barrier();
  __builtin_amdgcn_sched_barrier(0);
}

// m204 bijective chunked XCD swizzle for NWG=1564 (q=195, r=4)
__device__ __forceinline__ int xcd_map(int b) {
  int xcd = b & 7, pos = b >> 3;
  return (xcd < 4 ? xcd * 196 : 784 + (xcd - 4) * 195) + pos;
}

// ---------------- prep: weight transposes to bf16 ----------------
__global__ void prep_kernel(const float* __restrict__ W1, const float* __restrict__ W2,
                            ushort_t* __restrict__ W1T, ushort_t* __restrict__ W2T) {
  int i = blockIdx.x * 256 + threadIdx.x;
  if (i < 524288) {
    int n = i >> 10, k = i & 1023;
    W1T[i] = f2bf(W1[k * 512 + n]);             // W1T[n*1024+k]
  } else if (i < 786432) {
    int j = i - 524288;
    int n = j >> 9, k = j & 511;
    W2T[j] = f2bf(W2[k * 512 + n]);             // W2T[n*512+k]
  }
}

// ---------------- P2[g][n] = gp[g] @ W1[512:] + bias1 ----------------
__global__ __launch_bounds__(256, 4) void p2_kernel(
    const float* __restrict__ gp, const ushort_t* __restrict__ W1T,
    const float* __restrict__ bias1, float* __restrict__ P2) {
  const int tid = threadIdx.x, lane = tid & 63, wid = tid >> 6;
  const int lc = lane & 15, lr = lane >> 4;
  const int m0 = (blockIdx.x >> 1) * 32;
  const int col0 = (blockIdx.x & 1) * 256 + wid * 64;

  f32x4 acc[2][4];
#pragma unroll
  for (int i = 0; i < 2; ++i)
#pragma unroll
    for (int j = 0; j < 4; ++j) acc[i][j] = {0.f, 0.f, 0.f, 0.f};

  const float* a0 = gp + (size_t)(m0 + lc) * 512;
  const ushort_t* bb = W1T + (size_t)(col0 + lc) * 1024 + 512;

#pragma unroll 2
  for (int kt = 0; kt < 8; ++kt) {
    bf16x8 bfr[2][4];
#pragma unroll
    for (int kk = 0; kk < 2; ++kk)
#pragma unroll
      for (int j = 0; j < 4; ++j)
        bfr[kk][j] = *(const bf16x8*)(bb + (size_t)j * 16 * 1024 + kt * 64 + kk * 32 + lr * 8);
    bf16x8 af[2][2];
#pragma unroll
    for (int i = 0; i < 2; ++i)
#pragma unroll
      for (int kk = 0; kk < 2; ++kk)
        af[i][kk] = cvt8(a0 + (size_t)i * 16 * 512 + kt * 64 + kk * 32 + lr * 8);
#pragma unroll
    for (int kk = 0; kk < 2; ++kk)
#pragma unroll
      for (int i = 0; i < 2; ++i)
#pragma unroll
        for (int j = 0; j < 4; ++j)
          acc[i][j] = __builtin_amdgcn_mfma_f32_16x16x32_bf16(af[i][kk], bfr[kk][j], acc[i][j], 0, 0, 0);
  }

#pragma unroll
  for (int i = 0; i < 2; ++i)
#pragma unroll
    for (int r = 0; r < 4; ++r) {
      int row = m0 + i * 16 + lr * 4 + r;
#pragma unroll
      for (int j = 0; j < 4; ++j) {
        int col = col0 + j * 16 + lc;
        P2[(size_t)row * 512 + col] = acc[i][j][r] + bias1[col];
      }
    }
}

// ---------------- G1: h = relu(nf @ W1a + P2[bidx]); T14 reg-staged, 2 tiles ----------------
__global__ __launch_bounds__(256, 2) void g1_kernel(
    const float* __restrict__ nf, const int* __restrict__ bidx,
    const ushort_t* __restrict__ W1T, const float* __restrict__ P2,
    ushort_t* __restrict__ h) {
  __shared__ ushort_t sA[128 * 64];   // 16 KB bf16 A, chunk-swizzled (^row&7)
  __shared__ ushort_t sB[128 * 64];   // 16 KB bf16 B^T, chunk-swizzled

  const int tid = threadIdx.x, lane = tid & 63, wid = tid >> 6;
  const int wg = xcd_map(blockIdx.x);
  const int group = wg >> 2, nt = wg & 3;
  const int m0 = group * 256;         // tile0 rows m0.., tile1 rows m0+128..
  const int n0 = nt * 128;

  // chunk mapping (both A and B): q -> row=q>>3, phys slot=q&7, logical cw=slot^(row&7)
  int arow[4], acw[4];
  const float* pAg[4];                // A: fp32 source, 2 float4 per chunk
  const ushort_t* pB[4];              // B: bf16 source, 1 int4 per chunk
  int ldsQ[4];
#pragma unroll
  for (int s = 0; s < 4; ++s) {
    int q = s * 256 + tid;
    int row = q >> 3;
    int cw = (q & 7) ^ (row & 7);
    arow[s] = row; acw[s] = cw;
    int rowg = m0 + row; if (rowg > N_NODES - 1) rowg = N_NODES - 1;
    pAg[s] = nf + (size_t)rowg * 512 + cw * 8;
    pB[s]  = W1T + (size_t)(n0 + row) * 1024 + cw * 8;
    ldsQ[s] = q * 8;
  }

  f32x4 acc[4][4];
#pragma unroll
  for (int i = 0; i < 4; ++i)
#pragma unroll
    for (int j = 0; j < 4; ++j) acc[i][j] = {0.f, 0.f, 0.f, 0.f};

  const int wm = (wid >> 1) * 64, wn = (wid & 1) * 64;
  const int lr = lane >> 4, lc = lane & 15;

  // ---- prologue: stage step 0 ----
  {
    float4 ax[4], ay[4]; int4 bv[4];
#pragma unroll
    for (int s = 0; s < 4; ++s) {
      ax[s] = *(const float4*)(pAg[s]);
      ay[s] = *(const float4*)(pAg[s] + 4);
      bv[s] = *(const int4*)(pB[s]);
      pAg[s] += 64; pB[s] += 64;
    }
#pragma unroll
    for (int s = 0; s < 4; ++s) {
      *(bf16x8*)&sA[ldsQ[s]] = cvt8v(ax[s], ay[s]);
      *(int4*)&sB[ldsQ[s]] = bv[s];
    }
    __syncthreads();
  }

  float4 ax[4], ay[4]; int4 bvr[4];
#pragma unroll
  for (int s = 0; s < 16; ++s) {
    // ---- issue loads for step s+1 (consumed after compute) ----
    if (s < 15) {
      if (s == 7) {                   // next stage = tile1 step0
#pragma unroll
        for (int t = 0; t < 4; ++t) {
          int rowg = m0 + 128 + arow[t]; if (rowg > N_NODES - 1) rowg = N_NODES - 1;
          pAg[t] = nf + (size_t)rowg * 512 + acw[t] * 8;
          pB[t] -= 512;               // rewind B to k=0 (same tile for both mt)
        }
      }
#pragma unroll
      for (int t = 0; t < 4; ++t) {
        ax[t] = *(const float4*)(pAg[t]);
        ay[t] = *(const float4*)(pAg[t] + 4);
        bvr[t] = *(const int4*)(pB[t]);
        pAg[t] += 64; pB[t] += 64;
      }
    }
    // ---- compute step s (kt = s&7) ----
    __builtin_amdgcn_s_setprio(1);
#pragma unroll
    for (int kk = 0; kk < 2; ++kk) {
      bf16x8 af[4], bfr[4];
#pragma unroll
      for (int i = 0; i < 4; ++i) {
        int row = wm + i * 16 + lc;
        int cp = (kk * 4 + lr) ^ (row & 7);
        af[i] = *(const bf16x8*)&sA[row * 64 + cp * 8];
      }
#pragma unroll
      for (int j = 0; j < 4; ++j) {
        int col = wn + j * 16 + lc;
        int cp = (kk * 4 + lr) ^ (col & 7);
        bfr[j] = *(const bf16x8*)&sB[col * 64 + cp * 8];
      }
#pragma unroll
      for (int i = 0; i < 4; ++i)
#pragma unroll
        for (int j = 0; j < 4; ++j)
          acc[i][j] = __builtin_amdgcn_mfma_f32_16x16x32_bf16(af[i], bfr[j], acc[i][j], 0, 0, 0);
    }
    __builtin_amdgcn_s_setprio(0);

    // ---- publish step s+1 ----
    if (s < 15) {
      block_sync();                                  // everyone done reading s
#pragma unroll
      for (int t = 0; t < 4; ++t) {
        *(bf16x8*)&sA[ldsQ[t]] = cvt8v(ax[t], ay[t]);
        *(int4*)&sB[ldsQ[t]] = bvr[t];
      }
      asm volatile("s_waitcnt lgkmcnt(0)" ::: "memory");
      block_sync();                                  // s+1 visible
    }

    // ---- epilogue per tile ----
    if (s == 7 || s == 15) {
      const int m0t = m0 + (s >> 3) * 128;
#pragma unroll
      for (int i = 0; i < 4; ++i) {
#pragma unroll
        for (int r = 0; r < 4; ++r) {
          int row = m0t + wm + i * 16 + lr * 4 + r;
          if (row < N_NODES) {
            int g = bidx[row];
            const float* p2r = P2 + (size_t)g * 512 + n0 + wn;
#pragma unroll
            for (int j = 0; j < 4; ++j) {
              float v = fmaxf(acc[i][j][r] + p2r[j * 16 + lc], 0.f);
              h[(size_t)row * 512 + n0 + wn + j * 16 + lc] = f2bf(v);
            }
          }
        }
      }
      if (s == 7) {
#pragma unroll
        for (int i = 0; i < 4; ++i)
#pragma unroll
          for (int j = 0; j < 4; ++j) acc[i][j] = {0.f, 0.f, 0.f, 0.f};
      }
    }
  }
}

// ---------------- G2: out = h @ W2 + b2 (f32); T14 reg-staged, 2 tiles ----------------
__global__ __launch_bounds__(256, 2) void g2_kernel(
    const ushort_t* __restrict__ h, const ushort_t* __restrict__ W2T,
    const float* __restrict__ bias2, float* __restrict__ out) {
  __shared__ ushort_t sA[128 * 64];
  __shared__ ushort_t sB[128 * 64];

  const int tid = threadIdx.x, lane = tid & 63, wid = tid >> 6;
  const int wg = xcd_map(blockIdx.x);
  const int group = wg >> 2, nt = wg & 3;
  const int m0 = group * 256;
  const int n0 = nt * 128;

  int arow[4], acw[4];
  const ushort_t* pA[4];
  const ushort_t* pB[4];
  int ldsQ[4];
#pragma unroll
  for (int s = 0; s < 4; ++s) {
    int q = s * 256 + tid;
    int row = q >> 3;
    int cw = (q & 7) ^ (row & 7);
    arow[s] = row; acw[s] = cw;
    int rowg = m0 + row; if (rowg > N_NODES - 1) rowg = N_NODES - 1;
    pA[s] = h + (size_t)rowg * 512 + cw * 8;
    pB[s] = W2T + (size_t)(n0 + row) * 512 + cw * 8;
    ldsQ[s] = q * 8;
  }

  const int wm = (wid >> 1) * 64, wn = (wid & 1) * 64;
  const int lr = lane >> 4, lc = lane & 15;

  float bv2[4];
#pragma unroll
  for (int j = 0; j < 4; ++j) bv2[j] = bias2[n0 + wn + j * 16 + lc];

  f32x4 acc[4][4];
#pragma unroll
  for (int i = 0; i < 4; ++i)
#pragma unroll
    for (int j = 0; j < 4; ++j) acc[i][j] = {0.f, 0.f, 0.f, 0.f};

  // prologue: stage step 0
  {
    int4 av[4], bv[4];
#pragma unroll
    for (int s = 0; s < 4; ++s) {
      av[s] = *(const int4*)(pA[s]);
      bv[s] = *(const int4*)(pB[s]);
      pA[s] += 64; pB[s] += 64;
    }
#pragma unroll
    for (int s = 0; s < 4; ++s) {
      *(int4*)&sA[ldsQ[s]] = av[s];
      *(int4*)&sB[ldsQ[s]] = bv[s];
    }
    __syncthreads();
  }

  int4 avr[4], bvr[4];
#pragma unroll
  for (int s = 0; s < 16; ++s) {
    if (s < 15) {
      if (s == 7) {
#pragma unroll
        for (int t = 0; t < 4; ++t) {
          int rowg = m0 + 128 + arow[t]; if (rowg > N_NODES - 1) rowg = N_NODES - 1;
          pA[t] = h + (size_t)rowg * 512 + acw[t] * 8;
          pB[t] -= 512;
        }
      }
#pragma unroll
      for (int t = 0; t < 4; ++t) {
        avr[t] = *(const int4*)(pA[t]);
        bvr[t] = *(const int4*)(pB[t]);
        pA[t] += 64; pB[t] += 64;
      }
    }
    __builtin_amdgcn_s_setprio(1);
#pragma unroll
    for (int kk = 0; kk < 2; ++kk) {
      bf16x8 af[4], bfr[4];
#pragma unroll
      for (int i = 0; i < 4; ++i) {
        int row = wm + i * 16 + lc;
        int cp = (kk * 4 + lr) ^ (row & 7);
        af[i] = *(const bf16x8*)&sA[row * 64 + cp * 8];
      }
#pragma unroll
      for (int j = 0; j < 4; ++j) {
        int col = wn + j * 16 + lc;
        int cp = (kk * 4 + lr) ^ (col & 7);
        bfr[j] = *(const bf16x8*)&sB[col * 64 + cp * 8];
      }
#pragma unroll
      for (int i = 0; i < 4; ++i)
#pragma unroll
        for (int j = 0; j < 4; ++j)
          acc[i][j] = __builtin_amdgcn_mfma_f32_16x16x32_bf16(af[i], bfr[j], acc[i][j], 0, 0, 0);
    }
    __builtin_amdgcn_s_setprio(0);

    if (s < 15) {
      block_sync();
#pragma unroll
      for (int t = 0; t < 4; ++t) {
        *(int4*)&sA[ldsQ[t]] = avr[t];
        *(int4*)&sB[ldsQ[t]] = bvr[t];
      }
      asm volatile("s_waitcnt lgkmcnt(0)" ::: "memory");
      block_sync();
    }

    if (s == 7 || s == 15) {
      const int m0t = m0 + (s >> 3) * 128;
#pragma unroll
      for (int j = 0; j < 4; ++j) {
        int col = n0 + wn + j * 16 + lc;
#pragma unroll
        for (int i = 0; i < 4; ++i)
#pragma unroll
          for (int r = 0; r < 4; ++r) {
            int row = m0t + wm + i * 16 + lr * 4 + r;
            if (row < N_NODES) out[(size_t)row * 512 + col] = acc[i][j][r] + bv2[j];
          }
      }
      if (s == 7) {
#pragma unroll
        for (int i = 0; i < 4; ++i)
#pragma unroll
          for (int j = 0; j < 4; ++j) acc[i][j] = {0.f, 0.f, 0.f, 0.f};
      }
    }
  }
}

extern "C" void kernel_launch(void* const* d_in, const int* in_sizes, int n_in,
                              void* d_out, int out_size, void* d_ws, size_t ws_size,
                              hipStream_t stream) {
  const float* nf   = (const float*)d_in[0];   // [100000,512] f32
  const float* gp   = (const float*)d_in[1];   // [1024,512]  f32
  const int*   bidx = (const int*)d_in[2];     // [100000]    i32
  const float* W1   = (const float*)d_in[3];   // [1024,512]  f32
  const float* b1   = (const float*)d_in[4];   // [512]
  const float* W2   = (const float*)d_in[5];   // [512,512]   f32
  const float* b2   = (const float*)d_in[6];   // [512]
  float* out = (float*)d_out;

  char* ws = (char*)d_ws;
  ushort_t* W1T = (ushort_t*)ws;                  // 1,048,576 B
  ushort_t* W2T = (ushort_t*)(ws + 1048576);      //   524,288 B
  float*    P2  = (float*)   (ws + 1572864);      // 2,097,152 B
  ushort_t* hbf = (ushort_t*)(ws + 3670016);      // 102,400,000 B (total ~106 MB)

  prep_kernel<<<3072, 256, 0, stream>>>(W1, W2, W1T, W2T);
  p2_kernel<<<64, 256, 0, stream>>>(gp, W1T, b1, P2);
  g1_kernel<<<NWG, 256, 0, stream>>>(nf, bidx, W1T, P2, hbf);
  g2_kernel<<<NWG, 256, 0, stream>>>(hbf, W2T, b2, out);
}

// Round 12
// 377.945 us; speedup vs baseline: 1.5601x; 1.5601x over previous
//
#include <hip/hip_runtime.h>

// out = relu(concat(nf, prompt[bidx]) @ W1 + b1) @ W2 + b2
//   P2  = gp @ W1[512:] + b1               (tiny)
//   h   = relu(nf @ W1[:512] + P2[bidx])   (g1)
//   out = h @ W2 + b2                      (g2)
// Round 12: r8 skeleton + A-loads hoisted 1 iteration ahead + counted-vmcnt raw
// barriers (no vmcnt(0) drain in loop). Single 32 KB LDS buffer per kernel.

#define N_NODES 100000
#define NWG 3128                // 782 m-tiles * 4 n-tiles = 8 * 391 (bijective XCD chunks)

typedef __bf16 bf16x8 __attribute__((ext_vector_type(8)));
typedef float  f32x4  __attribute__((ext_vector_type(4)));
typedef unsigned short ushort_t;

__device__ __forceinline__ ushort_t f2bf(float f) {
  __bf16 b = (__bf16)f;
  return __builtin_bit_cast(unsigned short, b);
}

__device__ __forceinline__ bf16x8 cvt8(const float* p) {
  float4 x = *(const float4*)p;
  float4 y = *(const float4*)(p + 4);
  bf16x8 v;
  v[0] = (__bf16)x.x; v[1] = (__bf16)x.y; v[2] = (__bf16)x.z; v[3] = (__bf16)x.w;
  v[4] = (__bf16)y.x; v[5] = (__bf16)y.y; v[6] = (__bf16)y.z; v[7] = (__bf16)y.w;
  return v;
}

__device__ __forceinline__ bf16x8 cvt8v(float4 x, float4 y) {
  bf16x8 v;
  v[0] = (__bf16)x.x; v[1] = (__bf16)x.y; v[2] = (__bf16)x.z; v[3] = (__bf16)x.w;
  v[4] = (__bf16)y.x; v[5] = (__bf16)y.y; v[6] = (__bf16)y.z; v[7] = (__bf16)y.w;
  return v;
}

__device__ __forceinline__ void gload_lds16(const void* g, void* l) {
  __builtin_amdgcn_global_load_lds(
      (const __attribute__((address_space(1))) void*)g,
      (__attribute__((address_space(3))) void*)l, 16, 0, 0);
}

// ---------------- prep: weight transposes to bf16 ----------------
__global__ void prep_kernel(const float* __restrict__ W1, const float* __restrict__ W2,
                            ushort_t* __restrict__ W1T, ushort_t* __restrict__ W2T) {
  int i = blockIdx.x * 256 + threadIdx.x;
  if (i < 524288) {
    int n = i >> 10, k = i & 1023;
    W1T[i] = f2bf(W1[k * 512 + n]);             // W1T[n*1024+k]
  } else if (i < 786432) {
    int j = i - 524288;
    int n = j >> 9, k = j & 511;
    W2T[j] = f2bf(W2[k * 512 + n]);             // W2T[n*512+k]
  }
}

// ---------------- P2[g][n] = gp[g] @ W1[512:] + bias1 ----------------
__global__ __launch_bounds__(256, 4) void p2_kernel(
    const float* __restrict__ gp, const ushort_t* __restrict__ W1T,
    const float* __restrict__ bias1, float* __restrict__ P2) {
  const int tid = threadIdx.x, lane = tid & 63, wid = tid >> 6;
  const int lc = lane & 15, lr = lane >> 4;
  const int m0 = (blockIdx.x >> 1) * 32;
  const int col0 = (blockIdx.x & 1) * 256 + wid * 64;

  f32x4 acc[2][4];
#pragma unroll
  for (int i = 0; i < 2; ++i)
#pragma unroll
    for (int j = 0; j < 4; ++j) acc[i][j] = {0.f, 0.f, 0.f, 0.f};

  const float* a0 = gp + (size_t)(m0 + lc) * 512;
  const ushort_t* bb = W1T + (size_t)(col0 + lc) * 1024 + 512;

#pragma unroll 2
  for (int kt = 0; kt < 8; ++kt) {
    bf16x8 bfr[2][4];
#pragma unroll
    for (int kk = 0; kk < 2; ++kk)
#pragma unroll
      for (int j = 0; j < 4; ++j)
        bfr[kk][j] = *(const bf16x8*)(bb + (size_t)j * 16 * 1024 + kt * 64 + kk * 32 + lr * 8);
    bf16x8 af[2][2];
#pragma unroll
    for (int i = 0; i < 2; ++i)
#pragma unroll
      for (int kk = 0; kk < 2; ++kk)
        af[i][kk] = cvt8(a0 + (size_t)i * 16 * 512 + kt * 64 + kk * 32 + lr * 8);
#pragma unroll
    for (int kk = 0; kk < 2; ++kk)
#pragma unroll
      for (int i = 0; i < 2; ++i)
#pragma unroll
        for (int j = 0; j < 4; ++j)
          acc[i][j] = __builtin_amdgcn_mfma_f32_16x16x32_bf16(af[i][kk], bfr[kk][j], acc[i][j], 0, 0, 0);
  }

#pragma unroll
  for (int i = 0; i < 2; ++i)
#pragma unroll
    for (int r = 0; r < 4; ++r) {
      int row = m0 + i * 16 + lr * 4 + r;
#pragma unroll
      for (int j = 0; j < 4; ++j) {
        int col = col0 + j * 16 + lc;
        P2[(size_t)row * 512 + col] = acc[i][j][r] + bias1[col];
      }
    }
}

// ---------------- G1: h = relu(nf @ W1a + P2[bidx]); A hoisted 1-ahead ----------------
__global__ __launch_bounds__(256, 4) void g1_kernel(
    const float* __restrict__ nf, const int* __restrict__ bidx,
    const ushort_t* __restrict__ W1T, const float* __restrict__ P2,
    ushort_t* __restrict__ h) {
  __shared__ ushort_t sA[128 * 64];   // 16 KB bf16 A, chunk-swizzled (^row&7)
  __shared__ ushort_t sB[128 * 64];   // 16 KB bf16 B^T, chunk-swizzled

  const int tid = threadIdx.x, lane = tid & 63, wid = tid >> 6;
  const int tile = (blockIdx.x & 7) * 391 + (blockIdx.x >> 3);   // chunked XCD swizzle
  const int m0 = (tile >> 2) * 128, n0 = (tile & 3) * 128;

  // A: 4 chunks/thread (8 bf16), reg-staged from fp32 (2 float4 loads each)
  const float* pAg[4]; int ldsA[4];
#pragma unroll
  for (int s = 0; s < 4; ++s) {
    int q = s * 256 + tid;
    int row = q >> 3;
    int cw = (q & 7) ^ (row & 7);
    int rowg = m0 + row; if (rowg > N_NODES - 1) rowg = N_NODES - 1;
    pAg[s] = nf + (size_t)rowg * 512 + cw * 8;
    ldsA[s] = q * 8;
  }
  // B: 4 chunks/thread via global_load_lds (wave-uniform dest)
  const ushort_t* pB[4]; int ldsB[4];
#pragma unroll
  for (int s = 0; s < 4; ++s) {
    int q = wid * 256 + s * 64 + lane;
    int row = q >> 3;
    int cw = (q & 7) ^ (row & 7);
    pB[s] = W1T + (size_t)(n0 + row) * 1024 + cw * 8;
    ldsB[s] = (wid * 256 + s * 64) * 8;
  }

  f32x4 acc[4][4];
#pragma unroll
  for (int i = 0; i < 4; ++i)
#pragma unroll
    for (int j = 0; j < 4; ++j) acc[i][j] = {0.f, 0.f, 0.f, 0.f};

  const int wm = (wid >> 1) * 64, wn = (wid & 1) * 64;
  const int lr = lane >> 4, lc = lane & 15;

  // prologue: A(0) loads -> regs
  float4 ax[4], ay[4];
#pragma unroll
  for (int s = 0; s < 4; ++s) {
    ax[s] = *(const float4*)(pAg[s]);
    ay[s] = *(const float4*)(pAg[s] + 4);
    pAg[s] += 64;
  }

#pragma unroll
  for (int kt = 0; kt < 8; ++kt) {
    // stage A(t) from regs (cvt waits the 1-ahead loads; they've had a full period)
#pragma unroll
    for (int s = 0; s < 4; ++s)
      *(bf16x8*)&sA[ldsA[s]] = cvt8v(ax[s], ay[s]);
    // stage B(t): async global->LDS (L2-resident)
#pragma unroll
    for (int s = 0; s < 4; ++s) { gload_lds16(pB[s], &sB[ldsB[s]]); pB[s] += 64; }
    // prefetch A(t+1) -> regs (stays in flight across the barrier + compute)
    if (kt < 7) {
#pragma unroll
      for (int s = 0; s < 4; ++s) {
        ax[s] = *(const float4*)(pAg[s]);
        ay[s] = *(const float4*)(pAg[s] + 4);
        pAg[s] += 64;
      }
      // wait: B(t) 4 gload_lds landed + own ds_writes; A(t+1) 8 loads stay in flight
      asm volatile("s_waitcnt vmcnt(8) lgkmcnt(0)" ::: "memory");
    } else {
      asm volatile("s_waitcnt vmcnt(0) lgkmcnt(0)" ::: "memory");
    }
    __builtin_amdgcn_s_barrier();
    __builtin_amdgcn_sched_barrier(0);

    // compute(t): 32 MFMA
#pragma unroll
    for (int kk = 0; kk < 2; ++kk) {
      bf16x8 af[4], bfr[4];
#pragma unroll
      for (int i = 0; i < 4; ++i) {
        int row = wm + i * 16 + lc;
        int cp = (kk * 4 + lr) ^ (row & 7);
        af[i] = *(const bf16x8*)&sA[row * 64 + cp * 8];
      }
#pragma unroll
      for (int j = 0; j < 4; ++j) {
        int col = wn + j * 16 + lc;
        int cp = (kk * 4 + lr) ^ (col & 7);
        bfr[j] = *(const bf16x8*)&sB[col * 64 + cp * 8];
      }
#pragma unroll
      for (int i = 0; i < 4; ++i)
#pragma unroll
        for (int j = 0; j < 4; ++j)
          acc[i][j] = __builtin_amdgcn_mfma_f32_16x16x32_bf16(af[i], bfr[j], acc[i][j], 0, 0, 0);
    }
    if (kt < 7) {
      __builtin_amdgcn_s_barrier();     // raw: all waves done reading (t); no drain
      __builtin_amdgcn_sched_barrier(0);
    }
  }

  // epilogue: + P2[bidx[row]], relu, bf16 store
#pragma unroll
  for (int i = 0; i < 4; ++i) {
#pragma unroll
    for (int r = 0; r < 4; ++r) {
      int row = m0 + wm + i * 16 + lr * 4 + r;
      if (row < N_NODES) {
        int g = bidx[row];
        const float* p2r = P2 + (size_t)g * 512 + n0 + wn;
#pragma unroll
        for (int j = 0; j < 4; ++j) {
          float v = fmaxf(acc[i][j][r] + p2r[j * 16 + lc], 0.f);
          h[(size_t)row * 512 + n0 + wn + j * 16 + lc] = f2bf(v);
        }
      }
    }
  }
}

// ---------------- G2: out = h @ W2 + b2 (f32); A hoisted 1-ahead ----------------
__global__ __launch_bounds__(256, 4) void g2_kernel(
    const ushort_t* __restrict__ h, const ushort_t* __restrict__ W2T,
    const float* __restrict__ bias2, float* __restrict__ out) {
  __shared__ ushort_t sA[128 * 64];
  __shared__ ushort_t sB[128 * 64];

  const int tid = threadIdx.x, lane = tid & 63, wid = tid >> 6;
  const int tile = (blockIdx.x & 7) * 391 + (blockIdx.x >> 3);
  const int m0 = (tile >> 2) * 128, n0 = (tile & 3) * 128;

  // A (=h, HBM): 4 chunks/thread reg-staged; B (=W2T, L2): gload_lds
  const ushort_t* pAg[4]; int ldsA[4];
#pragma unroll
  for (int s = 0; s < 4; ++s) {
    int q = s * 256 + tid;
    int row = q >> 3;
    int cw = (q & 7) ^ (row & 7);
    int rowg = m0 + row; if (rowg > N_NODES - 1) rowg = N_NODES - 1;
    pAg[s] = h + (size_t)rowg * 512 + cw * 8;
    ldsA[s] = q * 8;
  }
  const ushort_t* pB[4]; int ldsB[4];
#pragma unroll
  for (int s = 0; s < 4; ++s) {
    int q = wid * 256 + s * 64 + lane;
    int row = q >> 3;
    int cw = (q & 7) ^ (row & 7);
    pB[s] = W2T + (size_t)(n0 + row) * 512 + cw * 8;
    ldsB[s] = (wid * 256 + s * 64) * 8;
  }

  f32x4 acc[4][4];
#pragma unroll
  for (int i = 0; i < 4; ++i)
#pragma unroll
    for (int j = 0; j < 4; ++j) acc[i][j] = {0.f, 0.f, 0.f, 0.f};

  const int wm = (wid >> 1) * 64, wn = (wid & 1) * 64;
  const int lr = lane >> 4, lc = lane & 15;

  // prologue: A(0) -> regs
  int4 av[4];
#pragma unroll
  for (int s = 0; s < 4; ++s) { av[s] = *(const int4*)(pAg[s]); pAg[s] += 64; }

#pragma unroll
  for (int kt = 0; kt < 8; ++kt) {
#pragma unroll
    for (int s = 0; s < 4; ++s)
      *(int4*)&sA[ldsA[s]] = av[s];                  // stage A(t) from regs
#pragma unroll
    for (int s = 0; s < 4; ++s) { gload_lds16(pB[s], &sB[ldsB[s]]); pB[s] += 64; }
    if (kt < 7) {
#pragma unroll
      for (int s = 0; s < 4; ++s) { av[s] = *(const int4*)(pAg[s]); pAg[s] += 64; }
      asm volatile("s_waitcnt vmcnt(4) lgkmcnt(0)" ::: "memory");   // B landed; A(t+1) in flight
    } else {
      asm volatile("s_waitcnt vmcnt(0) lgkmcnt(0)" ::: "memory");
    }
    __builtin_amdgcn_s_barrier();
    __builtin_amdgcn_sched_barrier(0);

#pragma unroll
    for (int kk = 0; kk < 2; ++kk) {
      bf16x8 af[4], bfr[4];
#pragma unroll
      for (int i = 0; i < 4; ++i) {
        int row = wm + i * 16 + lc;
        int cp = (kk * 4 + lr) ^ (row & 7);
        af[i] = *(const bf16x8*)&sA[row * 64 + cp * 8];
      }
#pragma unroll
      for (int j = 0; j < 4; ++j) {
        int col = wn + j * 16 + lc;
        int cp = (kk * 4 + lr) ^ (col & 7);
        bfr[j] = *(const bf16x8*)&sB[col * 64 + cp * 8];
      }
#pragma unroll
      for (int i = 0; i < 4; ++i)
#pragma unroll
        for (int j = 0; j < 4; ++j)
          acc[i][j] = __builtin_amdgcn_mfma_f32_16x16x32_bf16(af[i], bfr[j], acc[i][j], 0, 0, 0);
    }
    if (kt < 7) {
      __builtin_amdgcn_s_barrier();
      __builtin_amdgcn_sched_barrier(0);
    }
  }

#pragma unroll
  for (int j = 0; j < 4; ++j) {
    int col = n0 + wn + j * 16 + lc;
    float bv = bias2[col];
#pragma unroll
    for (int i = 0; i < 4; ++i)
#pragma unroll
      for (int r = 0; r < 4; ++r) {
        int row = m0 + wm + i * 16 + lr * 4 + r;
        if (row < N_NODES) out[(size_t)row * 512 + col] = acc[i][j][r] + bv;
      }
  }
}

extern "C" void kernel_launch(void* const* d_in, const int* in_sizes, int n_in,
                              void* d_out, int out_size, void* d_ws, size_t ws_size,
                              hipStream_t stream) {
  const float* nf   = (const float*)d_in[0];   // [100000,512] f32
  const float* gp   = (const float*)d_in[1];   // [1024,512]  f32
  const int*   bidx = (const int*)d_in[2];     // [100000]    i32
  const float* W1   = (const float*)d_in[3];   // [1024,512]  f32
  const float* b1   = (const float*)d_in[4];   // [512]
  const float* W2   = (const float*)d_in[5];   // [512,512]   f32
  const float* b2   = (const float*)d_in[6];   // [512]
  float* out = (float*)d_out;

  char* ws = (char*)d_ws;
  ushort_t* W1T = (ushort_t*)ws;                  // 1,048,576 B
  ushort_t* W2T = (ushort_t*)(ws + 1048576);      //   524,288 B
  float*    P2  = (float*)   (ws + 1572864);      // 2,097,152 B
  ushort_t* hbf = (ushort_t*)(ws + 3670016);      // 102,400,000 B (total ~106 MB)

  prep_kernel<<<3072, 256, 0, stream>>>(W1, W2, W1T, W2T);
  p2_kernel<<<64, 256, 0, stream>>>(gp, W1T, b1, P2);
  g1_kernel<<<NWG, 256, 0, stream>>>(nf, bidx, W1T, P2, hbf);
  g2_kernel<<<NWG, 256, 0, stream>>>(hbf, W2T, b2, out);
}

// Round 13
// 281.113 us; speedup vs baseline: 2.0975x; 1.3445x over previous
//
#include <hip/hip_runtime.h>

// out = relu(concat(nf, prompt[bidx]) @ W1 + b1) @ W2 + b2
//   P2  = gp @ W1[512:] + b1               (tiny)
//   h   = relu(nf @ W1[:512] + P2[bidx])   (g1)
//   out = h @ W2 + b2                      (g2)
// Round 13: r8's proven 1-phase schedule, widened to BN=256 with 512 threads
// (8 waves 2m x 4n). Halves per-CU L2 traffic for A; doubles compute/barrier.

#define N_NODES 100000
#define NWG 1564                // 782 m-tiles * 2 n-tiles; 1564 = 8*195+4 (bijective swizzle)

typedef __bf16 bf16x8 __attribute__((ext_vector_type(8)));
typedef float  f32x4  __attribute__((ext_vector_type(4)));
typedef unsigned short ushort_t;

__device__ __forceinline__ ushort_t f2bf(float f) {
  __bf16 b = (__bf16)f;
  return __builtin_bit_cast(unsigned short, b);
}

__device__ __forceinline__ bf16x8 cvt8(const float* p) {
  float4 x = *(const float4*)p;
  float4 y = *(const float4*)(p + 4);
  bf16x8 v;
  v[0] = (__bf16)x.x; v[1] = (__bf16)x.y; v[2] = (__bf16)x.z; v[3] = (__bf16)x.w;
  v[4] = (__bf16)y.x; v[5] = (__bf16)y.y; v[6] = (__bf16)y.z; v[7] = (__bf16)y.w;
  return v;
}

__device__ __forceinline__ bf16x8 cvt8v(float4 x, float4 y) {
  bf16x8 v;
  v[0] = (__bf16)x.x; v[1] = (__bf16)x.y; v[2] = (__bf16)x.z; v[3] = (__bf16)x.w;
  v[4] = (__bf16)y.x; v[5] = (__bf16)y.y; v[6] = (__bf16)y.z; v[7] = (__bf16)y.w;
  return v;
}

__device__ __forceinline__ void gload_lds16(const void* g, void* l) {
  __builtin_amdgcn_global_load_lds(
      (const __attribute__((address_space(1))) void*)g,
      (__attribute__((address_space(3))) void*)l, 16, 0, 0);
}

// m204 bijective chunked XCD swizzle for NWG=1564 (q=195, r=4)
__device__ __forceinline__ int xcd_map(int b) {
  int xcd = b & 7, pos = b >> 3;
  return (xcd < 4 ? xcd * 196 : 784 + (xcd - 4) * 195) + pos;
}

// ---------------- prep: weight transposes to bf16 ----------------
__global__ void prep_kernel(const float* __restrict__ W1, const float* __restrict__ W2,
                            ushort_t* __restrict__ W1T, ushort_t* __restrict__ W2T) {
  int i = blockIdx.x * 256 + threadIdx.x;
  if (i < 524288) {
    int n = i >> 10, k = i & 1023;
    W1T[i] = f2bf(W1[k * 512 + n]);             // W1T[n*1024+k]
  } else if (i < 786432) {
    int j = i - 524288;
    int n = j >> 9, k = j & 511;
    W2T[j] = f2bf(W2[k * 512 + n]);             // W2T[n*512+k]
  }
}

// ---------------- P2[g][n] = gp[g] @ W1[512:] + bias1 ----------------
__global__ __launch_bounds__(256, 4) void p2_kernel(
    const float* __restrict__ gp, const ushort_t* __restrict__ W1T,
    const float* __restrict__ bias1, float* __restrict__ P2) {
  const int tid = threadIdx.x, lane = tid & 63, wid = tid >> 6;
  const int lc = lane & 15, lr = lane >> 4;
  const int m0 = (blockIdx.x >> 1) * 32;
  const int col0 = (blockIdx.x & 1) * 256 + wid * 64;

  f32x4 acc[2][4];
#pragma unroll
  for (int i = 0; i < 2; ++i)
#pragma unroll
    for (int j = 0; j < 4; ++j) acc[i][j] = {0.f, 0.f, 0.f, 0.f};

  const float* a0 = gp + (size_t)(m0 + lc) * 512;
  const ushort_t* bb = W1T + (size_t)(col0 + lc) * 1024 + 512;

#pragma unroll 2
  for (int kt = 0; kt < 8; ++kt) {
    bf16x8 bfr[2][4];
#pragma unroll
    for (int kk = 0; kk < 2; ++kk)
#pragma unroll
      for (int j = 0; j < 4; ++j)
        bfr[kk][j] = *(const bf16x8*)(bb + (size_t)j * 16 * 1024 + kt * 64 + kk * 32 + lr * 8);
    bf16x8 af[2][2];
#pragma unroll
    for (int i = 0; i < 2; ++i)
#pragma unroll
      for (int kk = 0; kk < 2; ++kk)
        af[i][kk] = cvt8(a0 + (size_t)i * 16 * 512 + kt * 64 + kk * 32 + lr * 8);
#pragma unroll
    for (int kk = 0; kk < 2; ++kk)
#pragma unroll
      for (int i = 0; i < 2; ++i)
#pragma unroll
        for (int j = 0; j < 4; ++j)
          acc[i][j] = __builtin_amdgcn_mfma_f32_16x16x32_bf16(af[i][kk], bfr[kk][j], acc[i][j], 0, 0, 0);
  }

#pragma unroll
  for (int i = 0; i < 2; ++i)
#pragma unroll
    for (int r = 0; r < 4; ++r) {
      int row = m0 + i * 16 + lr * 4 + r;
#pragma unroll
      for (int j = 0; j < 4; ++j) {
        int col = col0 + j * 16 + lc;
        P2[(size_t)row * 512 + col] = acc[i][j][r] + bias1[col];
      }
    }
}

// ---------------- G1: h = relu(nf @ W1a + P2[bidx]); BM=128 BN=256, 512 thr ----------------
__global__ __launch_bounds__(512, 4) void g1_kernel(
    const float* __restrict__ nf, const int* __restrict__ bidx,
    const ushort_t* __restrict__ W1T, const float* __restrict__ P2,
    ushort_t* __restrict__ h) {
  __shared__ ushort_t sA[128 * 64];   // 16 KB bf16 A, chunk-swizzled (^row&7)
  __shared__ ushort_t sB[256 * 64];   // 32 KB bf16 B^T (256 cols), chunk-swizzled

  const int tid = threadIdx.x, lane = tid & 63, wid = tid >> 6;
  const int wg = xcd_map(blockIdx.x);
  const int m0 = (wg >> 1) * 128, n0 = (wg & 1) * 256;

  // A: 2 chunks/thread (8 bf16 each), reg-staged from fp32
  const float* pAg[2]; int ldsA[2];
#pragma unroll
  for (int s = 0; s < 2; ++s) {
    int q = s * 512 + tid;              // 1024 chunks: row=q>>3 (0..127), slot=q&7
    int row = q >> 3;
    int cw = (q & 7) ^ (row & 7);
    int rowg = m0 + row; if (rowg > N_NODES - 1) rowg = N_NODES - 1;
    pAg[s] = nf + (size_t)rowg * 512 + cw * 8;
    ldsA[s] = q * 8;
  }
  // B: 4 chunks/thread via global_load_lds (2048 chunks, wave-uniform dest)
  const ushort_t* pB[4]; int ldsB[4];
#pragma unroll
  for (int s = 0; s < 4; ++s) {
    int q = wid * 256 + s * 64 + lane;  // 0..2047: row=q>>3 (0..255)
    int row = q >> 3;
    int cw = (q & 7) ^ (row & 7);
    pB[s] = W1T + (size_t)(n0 + row) * 1024 + cw * 8;
    ldsB[s] = (wid * 256 + s * 64) * 8;
  }

  f32x4 acc[4][4];
#pragma unroll
  for (int i = 0; i < 4; ++i)
#pragma unroll
    for (int j = 0; j < 4; ++j) acc[i][j] = {0.f, 0.f, 0.f, 0.f};

  const int wm = (wid >> 2) * 64;       // 2 m-groups
  const int wn = (wid & 3) * 64;        // 4 n-groups
  const int lr = lane >> 4, lc = lane & 15;

  for (int kt = 0; kt < 8; ++kt) {
    // A fp32 loads first (T14: issue early)
    float4 ax[2], ay[2];
#pragma unroll
    for (int s = 0; s < 2; ++s) {
      ax[s] = *(const float4*)(pAg[s]);
      ay[s] = *(const float4*)(pAg[s] + 4);
      pAg[s] += 64;
    }
    // B async global->LDS
#pragma unroll
    for (int s = 0; s < 4; ++s) { gload_lds16(pB[s], &sB[ldsB[s]]); pB[s] += 64; }
    // cvt + LDS write
#pragma unroll
    for (int s = 0; s < 2; ++s)
      *(bf16x8*)&sA[ldsA[s]] = cvt8v(ax[s], ay[s]);
    __syncthreads();

#pragma unroll
    for (int kk = 0; kk < 2; ++kk) {
      bf16x8 af[4], bfr[4];
#pragma unroll
      for (int i = 0; i < 4; ++i) {
        int row = wm + i * 16 + lc;
        int cp = (kk * 4 + lr) ^ (row & 7);
        af[i] = *(const bf16x8*)&sA[row * 64 + cp * 8];
      }
#pragma unroll
      for (int j = 0; j < 4; ++j) {
        int col = wn + j * 16 + lc;
        int cp = (kk * 4 + lr) ^ (col & 7);
        bfr[j] = *(const bf16x8*)&sB[col * 64 + cp * 8];
      }
#pragma unroll
      for (int i = 0; i < 4; ++i)
#pragma unroll
        for (int j = 0; j < 4; ++j)
          acc[i][j] = __builtin_amdgcn_mfma_f32_16x16x32_bf16(af[i], bfr[j], acc[i][j], 0, 0, 0);
    }
    __syncthreads();
  }

  // epilogue: + P2[bidx[row]], relu, bf16 store
#pragma unroll
  for (int i = 0; i < 4; ++i) {
#pragma unroll
    for (int r = 0; r < 4; ++r) {
      int row = m0 + wm + i * 16 + lr * 4 + r;
      if (row < N_NODES) {
        int g = bidx[row];
        const float* p2r = P2 + (size_t)g * 512 + n0 + wn;
#pragma unroll
        for (int j = 0; j < 4; ++j) {
          float v = fmaxf(acc[i][j][r] + p2r[j * 16 + lc], 0.f);
          h[(size_t)row * 512 + n0 + wn + j * 16 + lc] = f2bf(v);
        }
      }
    }
  }
}

// ---------------- G2: out = h @ W2 + b2 (f32); BM=128 BN=256, 512 thr ----------------
__global__ __launch_bounds__(512, 4) void g2_kernel(
    const ushort_t* __restrict__ h, const ushort_t* __restrict__ W2T,
    const float* __restrict__ bias2, float* __restrict__ out) {
  __shared__ ushort_t sA[128 * 64];   // 16 KB
  __shared__ ushort_t sB[256 * 64];   // 32 KB

  const int tid = threadIdx.x, lane = tid & 63, wid = tid >> 6;
  const int wg = xcd_map(blockIdx.x);
  const int m0 = (wg >> 1) * 128, n0 = (wg & 1) * 256;

  // A (=h bf16): 2 chunks/thread via gload_lds (wave-uniform: q = s*512 + wid*64 + lane)
  const ushort_t* pA[2]; int ldsA[2];
#pragma unroll
  for (int s = 0; s < 2; ++s) {
    int q = s * 512 + tid;
    int row = q >> 3;
    int cw = (q & 7) ^ (row & 7);
    int rowg = m0 + row; if (rowg > N_NODES - 1) rowg = N_NODES - 1;
    pA[s] = h + (size_t)rowg * 512 + cw * 8;
    ldsA[s] = (s * 512 + wid * 64) * 8;   // wave-uniform base; lane*16B implicit
  }
  // B: 4 chunks/thread via gload_lds
  const ushort_t* pB[4]; int ldsB[4];
#pragma unroll
  for (int s = 0; s < 4; ++s) {
    int q = wid * 256 + s * 64 + lane;
    int row = q >> 3;
    int cw = (q & 7) ^ (row & 7);
    pB[s] = W2T + (size_t)(n0 + row) * 512 + cw * 8;
    ldsB[s] = (wid * 256 + s * 64) * 8;
  }

  f32x4 acc[4][4];
#pragma unroll
  for (int i = 0; i < 4; ++i)
#pragma unroll
    for (int j = 0; j < 4; ++j) acc[i][j] = {0.f, 0.f, 0.f, 0.f};

  const int wm = (wid >> 2) * 64;
  const int wn = (wid & 3) * 64;
  const int lr = lane >> 4, lc = lane & 15;

  for (int kt = 0; kt < 8; ++kt) {
#pragma unroll
    for (int s = 0; s < 2; ++s) { gload_lds16(pA[s], &sA[ldsA[s]]); pA[s] += 64; }
#pragma unroll
    for (int s = 0; s < 4; ++s) { gload_lds16(pB[s], &sB[ldsB[s]]); pB[s] += 64; }
    __syncthreads();

#pragma unroll
    for (int kk = 0; kk < 2; ++kk) {
      bf16x8 af[4], bfr[4];
#pragma unroll
      for (int i = 0; i < 4; ++i) {
        int row = wm + i * 16 + lc;
        int cp = (kk * 4 + lr) ^ (row & 7);
        af[i] = *(const bf16x8*)&sA[row * 64 + cp * 8];
      }
#pragma unroll
      for (int j = 0; j < 4; ++j) {
        int col = wn + j * 16 + lc;
        int cp = (kk * 4 + lr) ^ (col & 7);
        bfr[j] = *(const bf16x8*)&sB[col * 64 + cp * 8];
      }
#pragma unroll
      for (int i = 0; i < 4; ++i)
#pragma unroll
        for (int j = 0; j < 4; ++j)
          acc[i][j] = __builtin_amdgcn_mfma_f32_16x16x32_bf16(af[i], bfr[j], acc[i][j], 0, 0, 0);
    }
    __syncthreads();
  }

#pragma unroll
  for (int j = 0; j < 4; ++j) {
    int col = n0 + wn + j * 16 + lc;
    float bv = bias2[col];
#pragma unroll
    for (int i = 0; i < 4; ++i)
#pragma unroll
      for (int r = 0; r < 4; ++r) {
        int row = m0 + wm + i * 16 + lr * 4 + r;
        if (row < N_NODES) out[(size_t)row * 512 + col] = acc[i][j][r] + bv;
      }
  }
}

extern "C" void kernel_launch(void* const* d_in, const int* in_sizes, int n_in,
                              void* d_out, int out_size, void* d_ws, size_t ws_size,
                              hipStream_t stream) {
  const float* nf   = (const float*)d_in[0];   // [100000,512] f32
  const float* gp   = (const float*)d_in[1];   // [1024,512]  f32
  const int*   bidx = (const int*)d_in[2];     // [100000]    i32
  const float* W1   = (const float*)d_in[3];   // [1024,512]  f32
  const float* b1   = (const float*)d_in[4];   // [512]
  const float* W2   = (const float*)d_in[5];   // [512,512]   f32
  const float* b2   = (const float*)d_in[6];   // [512]
  float* out = (float*)d_out;

  char* ws = (char*)d_ws;
  ushort_t* W1T = (ushort_t*)ws;                  // 1,048,576 B
  ushort_t* W2T = (ushort_t*)(ws + 1048576);      //   524,288 B
  float*    P2  = (float*)   (ws + 1572864);      // 2,097,152 B
  ushort_t* hbf = (ushort_t*)(ws + 3670016);      // 102,400,000 B (total ~106 MB)

  prep_kernel<<<3072, 256, 0, stream>>>(W1, W2, W1T, W2T);
  p2_kernel<<<64, 256, 0, stream>>>(gp, W1T, b1, P2);
  g1_kernel<<<NWG, 512, 0, stream>>>(nf, bidx, W1T, P2, hbf);
  g2_kernel<<<NWG, 512, 0, stream>>>(hbf, W2T, b2, out);
}